// Round 1
// baseline (439.015 us; speedup 1.0000x reference)
//
#include <hip/hip_runtime.h>
#include <stdint.h>

#define BB 4
#define TT 2048
#define CC 1024
#define HH 16
#define HD 64
#define C3 3072
#define MM (BB*TT)   // 8192 rows

typedef __bf16 bf16_t;
typedef bf16_t bf16x8 __attribute__((ext_vector_type(8)));
typedef float f32x4 __attribute__((ext_vector_type(4)));
typedef unsigned short u16;
typedef u16 u16x8 __attribute__((ext_vector_type(8)));
typedef uint32_t u32;

// f32 -> bf16 round-to-nearest-even
static __device__ __forceinline__ u16 f2bf(float f){
  u32 u = __builtin_bit_cast(u32, f);
  u32 r = (u + 0x7fffu + ((u >> 16) & 1u)) >> 16;
  return (u16)r;
}

static __device__ __forceinline__ f32x4 mfma16(bf16x8 a, bf16x8 b, f32x4 c){
  return __builtin_amdgcn_mfma_f32_16x16x32_bf16(a, b, c, 0, 0, 0);
}

typedef __attribute__((address_space(1))) void* gas_t;
typedef __attribute__((address_space(3))) void* las_t;
static __device__ __forceinline__ void gload16(const void* g, void* l){
  __builtin_amdgcn_global_load_lds((gas_t)g, (las_t)l, 16, 0, 0);
}

// ---------------- fp32 -> bf16 conversion (vectorized) ----------------
__global__ __launch_bounds__(256) void cvt_bf16(const float* __restrict__ in,
                                                u16* __restrict__ out, int n8){
  int stride = gridDim.x * blockDim.x;
  for (int i = blockIdx.x * blockDim.x + threadIdx.x; i < n8; i += stride){
    const float4* p = (const float4*)in + (size_t)i * 2;
    float4 a = p[0], b = p[1];
    u16x8 o;
    o[0]=f2bf(a.x); o[1]=f2bf(a.y); o[2]=f2bf(a.z); o[3]=f2bf(a.w);
    o[4]=f2bf(b.x); o[5]=f2bf(b.y); o[6]=f2bf(b.z); o[7]=f2bf(b.w);
    *((u16x8*)out + i) = o;
  }
}

// ---------------- bt-GEMM: C[M,N] = A[M,K] * B[N,K]^T  (m97 structure) --------
// 128x128 tile, BK=32, 256 threads = 4 waves (2x2), each wave 64x64 = 4x4 frags.
template<int OUTBF>
__global__ __launch_bounds__(256) void gemm_bt(const u16* __restrict__ A,
                                               const u16* __restrict__ Bm,
                                               void* __restrict__ Cp,
                                               int M, int N, int K){
  __shared__ u16 As[128*32];
  __shared__ u16 Bs[128*32];
  const int tid  = threadIdx.x;
  const int lane = tid & 63;
  const int w    = tid >> 6;
  const int m0   = blockIdx.y * 128;
  const int n0   = blockIdx.x * 128;
  const int wm   = (w >> 1) * 64;
  const int wn   = (w & 1) * 64;
  const int lr   = lane & 15;
  const int lkb  = (lane >> 4) * 16;   // byte offset of this lane's k-chunk

  f32x4 acc[4][4] = {};

  // staging: LDS linear [128][32] bf16; wave covers 2KB; lane writes 16B x2
  const int r0 = w*32 + (lane >> 2);
  const int c8 = (lane & 3) * 8;
  const u16* gA = A  + (size_t)(m0 + r0) * K + c8;
  const u16* gB = Bm + (size_t)(n0 + r0) * K + c8;
  char* lA = (char*)As + w*2048 + lane*16;
  char* lB = (char*)Bs + w*2048 + lane*16;

  for (int k0 = 0; k0 < K; k0 += 32){
    gload16(gA + k0,                 lA);
    gload16(gA + (size_t)16*K + k0,  lA + 1024);
    gload16(gB + k0,                 lB);
    gload16(gB + (size_t)16*K + k0,  lB + 1024);
    __syncthreads();
    bf16x8 af[4], bfr[4];
    #pragma unroll
    for (int m = 0; m < 4; m++)
      af[m] = *(const bf16x8*)((const char*)As + (wm + m*16 + lr)*64 + lkb);
    #pragma unroll
    for (int n = 0; n < 4; n++)
      bfr[n] = *(const bf16x8*)((const char*)Bs + (wn + n*16 + lr)*64 + lkb);
    #pragma unroll
    for (int m = 0; m < 4; m++)
      #pragma unroll
      for (int n = 0; n < 4; n++)
        acc[m][n] = mfma16(af[m], bfr[n], acc[m][n]);
    __syncthreads();
  }

  // epilogue: D row = (lane>>4)*4 + j, col = lane&15  [m89 layout]
  const int cr = (lane >> 4) * 4;
  #pragma unroll
  for (int m = 0; m < 4; m++)
    #pragma unroll
    for (int n = 0; n < 4; n++)
      #pragma unroll
      for (int j = 0; j < 4; j++){
        size_t row = (size_t)(m0 + wm + m*16 + cr + j);
        size_t col = (size_t)(n0 + wn + n*16 + lr);
        if (OUTBF) ((u16*)Cp)[row*(size_t)N + col] = f2bf(acc[m][n][j]);
        else       ((float*)Cp)[row*(size_t)N + col] = acc[m][n][j];
      }
}

// ---------------- flash attention (causal), bf16 in/out ----------------
// grid (T/64, H, B), 256 thr = 4 waves; wave w owns q rows [w*16, w*16+16)
__global__ __launch_bounds__(256) void attn_fwd(const u16* __restrict__ qkv,
                                                u16* __restrict__ y){
  __shared__ u16 Kl[64*72];      // K tile  [k][d], rows padded to 72
  __shared__ u16 Vt[64*72];      // V tile transposed [d][k], padded
  __shared__ u16 Pl[4][16*72];   // per-wave P [q16][k], padded
  const int qt = blockIdx.x, h = blockIdx.y, b = blockIdx.z;
  const int tid = threadIdx.x, lane = tid & 63, w = tid >> 6;
  const int lr = lane & 15, lg = lane >> 4;
  const size_t base = (size_t)b * TT * C3;

  // Q fragments straight from global (A-operand layout: row=lane%16, k=lg*8+j)
  bf16x8 qf0, qf1;
  {
    const u16* qp = qkv + base + (size_t)(qt*64 + w*16 + lr) * C3 + h*HD + lg*8;
    qf0 = *(const bf16x8*)qp;
    qf1 = *(const bf16x8*)(qp + 32);
  }

  f32x4 o[4] = {};
  float mj[4] = {-1e30f, -1e30f, -1e30f, -1e30f};
  float lj[4] = {0.f, 0.f, 0.f, 0.f};
  const float SC = 0.18033688011112042f;   // (1/8) * log2(e)

  const int sc8 = (tid & 7) * 8;           // staging col chunk

  for (int kt = 0; kt <= qt; kt++){
    __syncthreads();   // previous tile's LDS reads done before overwrite
    #pragma unroll
    for (int i = 0; i < 2; i++){
      int r = i*32 + (tid >> 3);
      const u16* kp = qkv + base + (size_t)(kt*64 + r) * C3 + CC + h*HD + sc8;
      *(u16x8*)&Kl[r*72 + sc8] = *(const u16x8*)kp;          // K row-major
      u16x8 vv = *(const u16x8*)(kp + CC);                   // V -> transposed
      #pragma unroll
      for (int e = 0; e < 8; e++) Vt[(sc8 + e)*72 + r] = vv[e];
    }
    __syncthreads();

    // S = Q K^T (scaled later): per wave 4 col-frags x 2 k-steps
    f32x4 s[4] = {};
    #pragma unroll
    for (int n = 0; n < 4; n++){
      bf16x8 kb0 = *(const bf16x8*)&Kl[(n*16 + lr)*72 + lg*8];
      bf16x8 kb1 = *(const bf16x8*)&Kl[(n*16 + lr)*72 + 32 + lg*8];
      s[n] = mfma16(qf0, kb0, s[n]);
      s[n] = mfma16(qf1, kb1, s[n]);
    }

    float t[4][4];
    #pragma unroll
    for (int n = 0; n < 4; n++)
      #pragma unroll
      for (int j = 0; j < 4; j++)
        t[n][j] = s[n][j] * SC;

    if (kt == qt){   // diagonal tile: mask k_local > q_local
      #pragma unroll
      for (int n = 0; n < 4; n++){
        int kl = n*16 + lr;
        #pragma unroll
        for (int j = 0; j < 4; j++){
          int ql = w*16 + lg*4 + j;
          if (kl > ql) t[n][j] = -1e30f;
        }
      }
    }

    // online softmax per q-row (row r lives in 16 lanes sharing lg, reg j)
    #pragma unroll
    for (int j = 0; j < 4; j++){
      float tm = fmaxf(fmaxf(t[0][j], t[1][j]), fmaxf(t[2][j], t[3][j]));
      #pragma unroll
      for (int d = 1; d < 16; d <<= 1) tm = fmaxf(tm, __shfl_xor(tm, d, 64));
      float mn = fmaxf(mj[j], tm);
      float al = __builtin_amdgcn_exp2f(mj[j] - mn);
      mj[j] = mn;
      float pj[4], ps = 0.f;
      #pragma unroll
      for (int n = 0; n < 4; n++){
        pj[n] = __builtin_amdgcn_exp2f(t[n][j] - mn);
        ps += pj[n];
      }
      #pragma unroll
      for (int d = 1; d < 16; d <<= 1) ps += __shfl_xor(ps, d, 64);
      lj[j] = lj[j]*al + ps;
      #pragma unroll
      for (int n = 0; n < 4; n++) o[n][j] *= al;
      #pragma unroll
      for (int n = 0; n < 4; n++)
        Pl[w][(lg*4 + j)*72 + n*16 + lr] = f2bf(pj[n]);   // wave-private
    }
    asm volatile("s_waitcnt lgkmcnt(0)" ::: "memory");    // P writes visible

    // O += P V
    #pragma unroll
    for (int ks = 0; ks < 2; ks++){
      bf16x8 pa = *(const bf16x8*)&Pl[w][lr*72 + ks*32 + lg*8];
      #pragma unroll
      for (int n = 0; n < 4; n++){
        bf16x8 vb = *(const bf16x8*)&Vt[(n*16 + lr)*72 + ks*32 + lg*8];
        o[n] = mfma16(pa, vb, o[n]);
      }
    }
  }

  // normalize + write y (bf16)
  #pragma unroll
  for (int j = 0; j < 4; j++){
    float inv = 1.0f / lj[j];
    size_t row = (size_t)b*TT + qt*64 + w*16 + lg*4 + j;
    #pragma unroll
    for (int n = 0; n < 4; n++)
      y[row*CC + h*HD + n*16 + lr] = f2bf(o[n][j] * inv);
  }
}

// ---------------- launch ----------------
extern "C" void kernel_launch(void* const* d_in, const int* in_sizes, int n_in,
                              void* d_out, int out_size, void* d_ws, size_t ws_size,
                              hipStream_t stream){
  const float* x     = (const float*)d_in[0];
  const float* w_in  = (const float*)d_in[1];
  const float* w_out = (const float*)d_in[2];
  float* out = (float*)d_out;

  u16* xb   = (u16*)d_ws;                  // 8192*1024  (reused as y after GEMM1)
  u16* wib  = xb  + (size_t)MM * CC;       // 3072*1024
  u16* wob  = wib + (size_t)C3 * CC;       // 1024*1024
  u16* qkvb = wob + (size_t)CC * CC;       // 8192*3072
  u16* yb   = xb;                          // x is dead after GEMM1

  auto nblk = [](int n8){ int g = (n8 + 255) / 256; return g > 2048 ? 2048 : g; };
  cvt_bf16<<<nblk(MM*CC/8), 256, 0, stream>>>(x,     xb,  MM*CC/8);
  cvt_bf16<<<nblk(C3*CC/8), 256, 0, stream>>>(w_in,  wib, C3*CC/8);
  cvt_bf16<<<nblk(CC*CC/8), 256, 0, stream>>>(w_out, wob, CC*CC/8);

  gemm_bt<1><<<dim3(C3/128, MM/128), 256, 0, stream>>>(xb, wib, (void*)qkvb, MM, C3, CC);
  attn_fwd<<<dim3(TT/64, HH, BB), 256, 0, stream>>>(qkvb, yb);
  gemm_bt<0><<<dim3(CC/128, MM/128), 256, 0, stream>>>(yb, wob, (void*)out, MM, CC, CC);
}

// Round 2
// 239.397 us; speedup vs baseline: 1.8338x; 1.8338x over previous
//
#include <hip/hip_runtime.h>
#include <stdint.h>

#define BB 4
#define TT 2048
#define CC 1024
#define HH 16
#define HD 64
#define C3 3072
#define MM (BB*TT)   // 8192 rows

typedef __bf16 bf16_t;
typedef bf16_t bf16x8 __attribute__((ext_vector_type(8)));
typedef float f32x4 __attribute__((ext_vector_type(4)));
typedef unsigned short u16;
typedef u16 u16x8 __attribute__((ext_vector_type(8)));
typedef uint32_t u32;

// f32 -> bf16 round-to-nearest-even
static __device__ __forceinline__ u16 f2bf(float f){
  u32 u = __builtin_bit_cast(u32, f);
  u32 r = (u + 0x7fffu + ((u >> 16) & 1u)) >> 16;
  return (u16)r;
}

static __device__ __forceinline__ f32x4 mfma16(bf16x8 a, bf16x8 b, f32x4 c){
  return __builtin_amdgcn_mfma_f32_16x16x32_bf16(a, b, c, 0, 0, 0);
}

typedef __attribute__((address_space(1))) void* gas_t;
typedef __attribute__((address_space(3))) void* las_t;
static __device__ __forceinline__ void gload16(const void* g, void* l){
  __builtin_amdgcn_global_load_lds((gas_t)g, (las_t)l, 16, 0, 0);
}

// ---------------- fp32 -> bf16 conversion (vectorized) ----------------
__global__ __launch_bounds__(256) void cvt_bf16(const float* __restrict__ in,
                                                u16* __restrict__ out, int n8){
  int stride = gridDim.x * blockDim.x;
  for (int i = blockIdx.x * blockDim.x + threadIdx.x; i < n8; i += stride){
    const float4* p = (const float4*)in + (size_t)i * 2;
    float4 a = p[0], b = p[1];
    u16x8 o;
    o[0]=f2bf(a.x); o[1]=f2bf(a.y); o[2]=f2bf(a.z); o[3]=f2bf(a.w);
    o[4]=f2bf(b.x); o[5]=f2bf(b.y); o[6]=f2bf(b.z); o[7]=f2bf(b.w);
    *((u16x8*)out + i) = o;
  }
}

// ---------------- bt-GEMM: C[M,N] = A[M,K] * B[N,K]^T  (m97 structure) --------
template<int OUTBF>
__global__ __launch_bounds__(256) void gemm_bt(const u16* __restrict__ A,
                                               const u16* __restrict__ Bm,
                                               void* __restrict__ Cp,
                                               int M, int N, int K){
  __shared__ u16 As[128*32];
  __shared__ u16 Bs[128*32];
  const int tid  = threadIdx.x;
  const int lane = tid & 63;
  const int w    = tid >> 6;
  const int m0   = blockIdx.y * 128;
  const int n0   = blockIdx.x * 128;
  const int wm   = (w >> 1) * 64;
  const int wn   = (w & 1) * 64;
  const int lr   = lane & 15;
  const int lkb  = (lane >> 4) * 16;

  f32x4 acc[4][4] = {};

  const int r0 = w*32 + (lane >> 2);
  const int c8 = (lane & 3) * 8;
  const u16* gA = A  + (size_t)(m0 + r0) * K + c8;
  const u16* gB = Bm + (size_t)(n0 + r0) * K + c8;
  char* lA = (char*)As + w*2048 + lane*16;
  char* lB = (char*)Bs + w*2048 + lane*16;

  for (int k0 = 0; k0 < K; k0 += 32){
    gload16(gA + k0,                 lA);
    gload16(gA + (size_t)16*K + k0,  lA + 1024);
    gload16(gB + k0,                 lB);
    gload16(gB + (size_t)16*K + k0,  lB + 1024);
    __syncthreads();
    bf16x8 af[4], bfr[4];
    #pragma unroll
    for (int m = 0; m < 4; m++)
      af[m] = *(const bf16x8*)((const char*)As + (wm + m*16 + lr)*64 + lkb);
    #pragma unroll
    for (int n = 0; n < 4; n++)
      bfr[n] = *(const bf16x8*)((const char*)Bs + (wn + n*16 + lr)*64 + lkb);
    #pragma unroll
    for (int m = 0; m < 4; m++)
      #pragma unroll
      for (int n = 0; n < 4; n++)
        acc[m][n] = mfma16(af[m], bfr[n], acc[m][n]);
    __syncthreads();
  }

  const int cr = (lane >> 4) * 4;
  #pragma unroll
  for (int m = 0; m < 4; m++)
    #pragma unroll
    for (int n = 0; n < 4; n++)
      #pragma unroll
      for (int j = 0; j < 4; j++){
        size_t row = (size_t)(m0 + wm + m*16 + cr + j);
        size_t col = (size_t)(n0 + wn + n*16 + lr);
        if (OUTBF) ((u16*)Cp)[row*(size_t)N + col] = f2bf(acc[m][n][j]);
        else       ((float*)Cp)[row*(size_t)N + col] = acc[m][n][j];
      }
}

// ---------------- flash attention (causal), bf16 in/out ----------------
// 1D grid, heavy-first: bid -> qtb = 15 - bid/64 (128 q-rows per block).
// 256 thr = 4 waves; wave w owns q rows {m*64 + w*16 + [0,16)} for m=0,1.
__global__ __launch_bounds__(256, 2) void attn_fwd(const u16* __restrict__ qkv,
                                                   u16* __restrict__ y){
  __shared__ u16 Kl[64*72];      // K tile [k][d], row stride 72 (odd*16B)
  __shared__ u16 Vt[64*72];      // V^T tile [d][k], row stride 72
  __shared__ u16 Pl[4][32*72];   // per-wave P [q32][k64], row stride 72
  const int bid = blockIdx.x;
  const int qtb = 15 - (bid >> 6);
  const int h = bid & 15, b = (bid >> 4) & 3;
  const int tid = threadIdx.x, lane = tid & 63, w = tid >> 6;
  const int lr = lane & 15, lg = lane >> 4;
  const size_t base = (size_t)b * TT * C3;
  const int q0 = qtb * 128;

  // Q fragments (A-operand): row = lr, d = ks*32 + lg*8 + j
  bf16x8 qf[2][2];
  #pragma unroll
  for (int m = 0; m < 2; m++){
    const u16* qp = qkv + base + (size_t)(q0 + m*64 + w*16 + lr) * C3 + h*HD;
    qf[m][0] = *(const bf16x8*)(qp + lg*8);
    qf[m][1] = *(const bf16x8*)(qp + 32 + lg*8);
  }

  // staging maps: K coalesced (row = tid>>3), V k-major lanes (row = tid&31)
  const int rK = tid >> 3, cK = tid & 7;
  const int rV = tid & 31, cV = tid >> 5;
  const u16* gK = qkv + base + (size_t)rK * C3 + CC   + h*HD + cK*8;
  const u16* gV = qkv + base + (size_t)rV * C3 + 2*CC + h*HD + cV*8;

  u16x8 kreg[2], vreg[2];
  kreg[0] = *(const u16x8*)(gK);
  kreg[1] = *(const u16x8*)(gK + (size_t)32*C3);
  vreg[0] = *(const u16x8*)(gV);
  vreg[1] = *(const u16x8*)(gV + (size_t)32*C3);

  f32x4 o[2][4] = {};
  float mj[2][4], lj[2][4];
  #pragma unroll
  for (int m = 0; m < 2; m++)
    #pragma unroll
    for (int j = 0; j < 4; j++){ mj[m][j] = -1e30f; lj[m][j] = 0.f; }
  const float SC = 0.18033688011112042f;   // (1/8) * log2(e)

  const int ktmax = 2*qtb + 1;
  for (int kt = 0; kt <= ktmax; kt++){
    __syncthreads();   // previous tile's LDS reads complete
    *(u16x8*)&Kl[rK*72 + cK*8] = kreg[0];
    *(u16x8*)&Kl[(rK+32)*72 + cK*8] = kreg[1];
    #pragma unroll
    for (int i = 0; i < 2; i++)
      #pragma unroll
      for (int e = 0; e < 8; e++)
        Vt[(cV*8+e)*72 + i*32 + rV] = vreg[i][e];
    __syncthreads();

    // prefetch next tile into regs (hides under compute)
    if (kt < ktmax){
      const u16* gk2 = gK + (size_t)(kt+1)*64*C3;
      const u16* gv2 = gV + (size_t)(kt+1)*64*C3;
      kreg[0] = *(const u16x8*)(gk2);
      kreg[1] = *(const u16x8*)(gk2 + (size_t)32*C3);
      vreg[0] = *(const u16x8*)(gv2);
      vreg[1] = *(const u16x8*)(gv2 + (size_t)32*C3);
    }

    // S = Q K^T : s[m][n], shared B-frags across m
    f32x4 s[2][4] = {};
    #pragma unroll
    for (int n = 0; n < 4; n++){
      bf16x8 kb0 = *(const bf16x8*)&Kl[(n*16+lr)*72 + lg*8];
      bf16x8 kb1 = *(const bf16x8*)&Kl[(n*16+lr)*72 + 32 + lg*8];
      #pragma unroll
      for (int m = 0; m < 2; m++){
        s[m][n] = mfma16(qf[m][0], kb0, s[m][n]);
        s[m][n] = mfma16(qf[m][1], kb1, s[m][n]);
      }
    }

    const bool domask = (kt >= 2*qtb);
    #pragma unroll
    for (int m = 0; m < 2; m++){
      #pragma unroll
      for (int j = 0; j < 4; j++){
        float t0 = s[m][0][j]*SC, t1 = s[m][1][j]*SC,
              t2 = s[m][2][j]*SC, t3 = s[m][3][j]*SC;
        if (domask){
          int q = q0 + m*64 + w*16 + lg*4 + j;
          int kb = kt*64 + lr;
          if (kb      > q) t0 = -1e30f;
          if (kb + 16 > q) t1 = -1e30f;
          if (kb + 32 > q) t2 = -1e30f;
          if (kb + 48 > q) t3 = -1e30f;
        }
        float tm = fmaxf(fmaxf(t0, t1), fmaxf(t2, t3));
        #pragma unroll
        for (int d = 1; d < 16; d <<= 1) tm = fmaxf(tm, __shfl_xor(tm, d, 64));
        float mo = mj[m][j];
        float mn = fmaxf(mo, tm);
        float al = __builtin_amdgcn_exp2f(mo - mn);
        mj[m][j] = mn;
        float p0 = __builtin_amdgcn_exp2f(t0 - mn);
        float p1 = __builtin_amdgcn_exp2f(t1 - mn);
        float p2 = __builtin_amdgcn_exp2f(t2 - mn);
        float p3 = __builtin_amdgcn_exp2f(t3 - mn);
        float ps = (p0 + p1) + (p2 + p3);
        #pragma unroll
        for (int d = 1; d < 16; d <<= 1) ps += __shfl_xor(ps, d, 64);
        lj[m][j] = lj[m][j]*al + ps;
        o[m][0][j] *= al; o[m][1][j] *= al; o[m][2][j] *= al; o[m][3][j] *= al;
        int prow = m*16 + lg*4 + j;
        Pl[w][prow*72 +      lr] = f2bf(p0);
        Pl[w][prow*72 + 16 + lr] = f2bf(p1);
        Pl[w][prow*72 + 32 + lr] = f2bf(p2);
        Pl[w][prow*72 + 48 + lr] = f2bf(p3);
      }
    }
    asm volatile("s_waitcnt lgkmcnt(0)" ::: "memory");

    // O += P V
    #pragma unroll
    for (int ks = 0; ks < 2; ks++){
      bf16x8 pa0 = *(const bf16x8*)&Pl[w][(lr     )*72 + ks*32 + lg*8];
      bf16x8 pa1 = *(const bf16x8*)&Pl[w][(16 + lr)*72 + ks*32 + lg*8];
      #pragma unroll
      for (int n = 0; n < 4; n++){
        bf16x8 vb = *(const bf16x8*)&Vt[(n*16+lr)*72 + ks*32 + lg*8];
        o[0][n] = mfma16(pa0, vb, o[0][n]);
        o[1][n] = mfma16(pa1, vb, o[1][n]);
      }
    }
  }

  // normalize + write y (bf16)
  #pragma unroll
  for (int m = 0; m < 2; m++)
    #pragma unroll
    for (int j = 0; j < 4; j++){
      float inv = 1.0f / lj[m][j];
      size_t row = (size_t)b*TT + q0 + m*64 + w*16 + lg*4 + j;
      #pragma unroll
      for (int n = 0; n < 4; n++)
        y[row*CC + h*HD + n*16 + lr] = f2bf(o[m][n][j] * inv);
    }
}

// ---------------- launch ----------------
extern "C" void kernel_launch(void* const* d_in, const int* in_sizes, int n_in,
                              void* d_out, int out_size, void* d_ws, size_t ws_size,
                              hipStream_t stream){
  const float* x     = (const float*)d_in[0];
  const float* w_in  = (const float*)d_in[1];
  const float* w_out = (const float*)d_in[2];
  float* out = (float*)d_out;

  u16* xb   = (u16*)d_ws;                  // 8192*1024  (reused as y after GEMM1)
  u16* wib  = xb  + (size_t)MM * CC;       // 3072*1024
  u16* wob  = wib + (size_t)C3 * CC;       // 1024*1024
  u16* qkvb = wob + (size_t)CC * CC;       // 8192*3072
  u16* yb   = xb;                          // x is dead after GEMM1

  auto nblk = [](int n8){ int g = (n8 + 255) / 256; return g > 2048 ? 2048 : g; };
  cvt_bf16<<<nblk(MM*CC/8), 256, 0, stream>>>(x,     xb,  MM*CC/8);
  cvt_bf16<<<nblk(C3*CC/8), 256, 0, stream>>>(w_in,  wib, C3*CC/8);
  cvt_bf16<<<nblk(CC*CC/8), 256, 0, stream>>>(w_out, wob, CC*CC/8);

  gemm_bt<1><<<dim3(C3/128, MM/128), 256, 0, stream>>>(xb, wib, (void*)qkvb, MM, C3, CC);
  attn_fwd<<<1024, 256, 0, stream>>>(qkvb, yb);
  gemm_bt<0><<<dim3(CC/128, MM/128), 256, 0, stream>>>(yb, wob, (void*)out, MM, CC, CC);
}